// Round 5
// baseline (263.303 us; speedup 1.0000x reference)
//
#include <hip/hip_runtime.h>
#include <hip/hip_fp16.h>

#define D 256
#define UN 8

typedef __attribute__((ext_vector_type(4))) _Float16 half4v;
typedef __attribute__((ext_vector_type(8))) _Float16 half8v;
typedef __attribute__((ext_vector_type(4))) float floatx4;

// ---------------- graph build ----------------

__global__ void count_deg(const int* __restrict__ dst, int E, int* __restrict__ cnt) {
    int e = blockIdx.x * blockDim.x + threadIdx.x;
    if (e < E) atomicAdd(&cnt[dst[e]], 1);
}

__global__ void scan_build(const int* __restrict__ cnt, int* __restrict__ row_ofs,
                           int* __restrict__ cursor, float* __restrict__ dinv, int n) {
    __shared__ int part[1024];
    int t = threadIdx.x;
    int CH = (n + 1023) >> 10;
    int base = t * CH;
    int sum = 0;
    for (int i = 0; i < CH; i++) { int idx = base + i; if (idx < n) sum += cnt[idx]; }
    part[t] = sum;
    __syncthreads();
    for (int off = 1; off < 1024; off <<= 1) {
        int v = (t >= off) ? part[t - off] : 0;
        __syncthreads();
        part[t] += v;
        __syncthreads();
    }
    int prefix = t ? part[t - 1] : 0;
    for (int i = 0; i < CH; i++) {
        int idx = base + i;
        if (idx < n) {
            int c = cnt[idx];
            row_ofs[idx] = prefix;
            cursor[idx] = prefix;
            dinv[idx] = rsqrtf((float)(c + 1));
            prefix += c;
        }
    }
    if (t == 1023) row_ofs[n] = part[1023];
}

__global__ void fill_csr(const int* __restrict__ src, const int* __restrict__ dst, int E,
                         int* __restrict__ cursor, int* __restrict__ csr_src) {
    int e = blockIdx.x * blockDim.x + threadIdx.x;
    if (e < E) {
        int d = dst[e];
        int pos = atomicAdd(&cursor[d], 1);
        csr_src[pos] = src[e];
    }
}

// ---------------- prep: W [k][n] fp32 -> WT [n][k] fp16 hi/lo ----------------
// one wave per output row n; lane owns k = lane*4 .. lane*4+3
__global__ void prep_w(const float* __restrict__ W, _Float16* __restrict__ WThi,
                       _Float16* __restrict__ WTlo) {
    int nrow = (blockIdx.x << 2) + (threadIdx.x >> 6);
    int lane = threadIdx.x & 63;
    int k0 = lane << 2;
    half4v h, l;
#pragma unroll
    for (int j = 0; j < 4; j++) {
        float v = W[(size_t)(k0 + j) * D + nrow];
        _Float16 hi = (_Float16)v;
        h[j] = hi;
        l[j] = (_Float16)(v - (float)hi);
    }
    *(half4v*)(WThi + (size_t)nrow * D + k0) = h;
    *(half4v*)(WTlo + (size_t)nrow * D + k0) = l;
}

// ---------------- prep: emb fp32 -> hi/lo fp16 ----------------
__global__ void prep_a(const float* __restrict__ A, _Float16* __restrict__ Ahi,
                       _Float16* __restrict__ Alo, int total4) {
    int i = blockIdx.x * blockDim.x + threadIdx.x;
    if (i >= total4) return;
    float4 v = ((const float4*)A)[i];
    half4v h, l;
    float vv[4] = {v.x, v.y, v.z, v.w};
#pragma unroll
    for (int j = 0; j < 4; j++) {
        _Float16 hi = (_Float16)vv[j];
        h[j] = hi;
        l[j] = (_Float16)(vv[j] - (float)hi);
    }
    ((half4v*)Ahi)[i] = h;
    ((half4v*)Alo)[i] = l;
}

// ---------------- MFMA GEMM: C[M,256] = A[M,256] x B[256,256], fp16-split, fp16 out ----
// one wave per 16x16 tile. A in hi/lo fp16 [m][k]; B pre-transposed hi/lo fp16 [n][k].
// 3 independent accumulator chains: hi*hi, hi*lo, lo*hi (~2^-22 rel precision).
// optional per-row scale (dinv) fused into epilogue.
__global__ void gemm_split(const _Float16* __restrict__ Ahi, const _Float16* __restrict__ Alo,
                           const _Float16* __restrict__ BThi, const _Float16* __restrict__ BTlo,
                           const float* __restrict__ scale, _Float16* __restrict__ C, int M) {
    int wave = threadIdx.x >> 6;
    int lane = threadIdx.x & 63;
    int mt = (blockIdx.x << 2) + wave;
    if (mt * 16 >= M) return;
    int m0 = mt << 4;
    int n0 = blockIdx.y << 4;
    int col = lane & 15;
    int quad = lane >> 4;
    const _Float16* ah = Ahi + (size_t)(m0 + col) * D + quad * 8;
    const _Float16* al = Alo + (size_t)(m0 + col) * D + quad * 8;
    const _Float16* bh = BThi + (size_t)(n0 + col) * D + quad * 8;
    const _Float16* bl = BTlo + (size_t)(n0 + col) * D + quad * 8;
    floatx4 acc0 = {0.f, 0.f, 0.f, 0.f};
    floatx4 acc1 = {0.f, 0.f, 0.f, 0.f};
    floatx4 acc2 = {0.f, 0.f, 0.f, 0.f};
#pragma unroll
    for (int k0 = 0; k0 < D; k0 += 32) {
        half8v a_h = *(const half8v*)(ah + k0);
        half8v a_l = *(const half8v*)(al + k0);
        half8v b_h = *(const half8v*)(bh + k0);
        half8v b_l = *(const half8v*)(bl + k0);
        acc0 = __builtin_amdgcn_mfma_f32_16x16x32_f16(a_h, b_h, acc0, 0, 0, 0);
        acc1 = __builtin_amdgcn_mfma_f32_16x16x32_f16(a_h, b_l, acc1, 0, 0, 0);
        acc2 = __builtin_amdgcn_mfma_f32_16x16x32_f16(a_l, b_h, acc2, 0, 0, 0);
    }
#pragma unroll
    for (int r = 0; r < 4; r++) {
        int row = m0 + quad * 4 + r;
        float v = acc0[r] + acc1[r] + acc2[r];
        if (scale) v *= scale[row];
        C[(size_t)row * D + n0 + col] = (_Float16)v;
    }
}

// ---------------- GCN aggregate ----------------
// xw1h rows pre-scaled by dinv[src]; agg = dinv[d] * (row_d + sum row_s); bias+relu;
// output split hi/lo fp16 for the next MFMA GEMM.
// csr indices staged lane-parallel in registers, broadcast via __shfl.
__global__ void gcn_agg(const _Float16* __restrict__ xw1h, const int* __restrict__ csr,
                        const int* __restrict__ row_ofs, const float* __restrict__ dinv,
                        const float* __restrict__ b1, _Float16* __restrict__ x1hi,
                        _Float16* __restrict__ x1lo, int n) {
    int node = (blockIdx.x << 2) + (threadIdx.x >> 6);
    if (node >= n) return;
    int lane = threadIdx.x & 63;
    int beg = row_ofs[node], end = row_ofs[node + 1];
    int deg = end - beg;
    int degc = deg < 256 ? deg : 256;
    // stage csr indices: lane-parallel coalesced loads
    int sreg[4];
#pragma unroll
    for (int c = 0; c < 4; c++) {
        int i = c * 64 + lane;
        sreg[c] = (i < deg) ? csr[beg + i] : 0;
    }
    float ax[UN][4];
#pragma unroll
    for (int j = 0; j < UN; j++) { ax[j][0] = ax[j][1] = ax[j][2] = ax[j][3] = 0.f; }
    {   // self loop (row already scaled by dinv[node])
        half4v v = ((const half4v*)(xw1h + (size_t)node * D))[lane];
        ax[0][0] = (float)v[0]; ax[0][1] = (float)v[1];
        ax[0][2] = (float)v[2]; ax[0][3] = (float)v[3];
    }
    for (int c = 0; c * 64 < degc; c++) {
        int cs = sreg[c];
        int lim = degc - c * 64;
        if (lim > 64) lim = 64;
        int i = 0;
        for (; i + UN <= lim; i += UN) {
#pragma unroll
            for (int j = 0; j < UN; j++) {
                int s = __shfl(cs, i + j);
                half4v u = ((const half4v*)(xw1h + (size_t)s * D))[lane];
                ax[j][0] += (float)u[0]; ax[j][1] += (float)u[1];
                ax[j][2] += (float)u[2]; ax[j][3] += (float)u[3];
            }
        }
        for (; i < lim; i++) {
            int s = __shfl(cs, i);
            half4v u = ((const half4v*)(xw1h + (size_t)s * D))[lane];
            ax[0][0] += (float)u[0]; ax[0][1] += (float)u[1];
            ax[0][2] += (float)u[2]; ax[0][3] += (float)u[3];
        }
    }
    for (int e = beg + 256; e < end; e++) {  // slow tail (deg>256; absent here)
        int s = csr[e];
        half4v u = ((const half4v*)(xw1h + (size_t)s * D))[lane];
        ax[0][0] += (float)u[0]; ax[0][1] += (float)u[1];
        ax[0][2] += (float)u[2]; ax[0][3] += (float)u[3];
    }
    float a0 = 0.f, a1 = 0.f, a2 = 0.f, a3 = 0.f;
#pragma unroll
    for (int j = 0; j < UN; j++) { a0 += ax[j][0]; a1 += ax[j][1]; a2 += ax[j][2]; a3 += ax[j][3]; }
    float dd = dinv[node];
    int c4 = lane * 4;
    float4 bb = *(const float4*)(b1 + c4);
    a0 = a0 * dd + bb.x; a1 = a1 * dd + bb.y; a2 = a2 * dd + bb.z; a3 = a3 * dd + bb.w;
    a0 = a0 > 0.f ? a0 : 0.f;
    a1 = a1 > 0.f ? a1 : 0.f;
    a2 = a2 > 0.f ? a2 : 0.f;
    a3 = a3 > 0.f ? a3 : 0.f;
    float av[4] = {a0, a1, a2, a3};
    half4v h, l;
#pragma unroll
    for (int j = 0; j < 4; j++) {
        _Float16 hi = (_Float16)av[j];
        h[j] = hi;
        l[j] = (_Float16)(av[j] - (float)hi);
    }
    *(half4v*)(x1hi + (size_t)node * D + c4) = h;
    *(half4v*)(x1lo + (size_t)node * D + c4) = l;
}

// ---------------- per-node attention dot products ----------------
__global__ void att_dots(const _Float16* __restrict__ xw2, const float* __restrict__ att_s,
                         const float* __restrict__ att_d, float* __restrict__ asrc,
                         float* __restrict__ adst, int n) {
    int node = (blockIdx.x << 2) + (threadIdx.x >> 6);
    if (node >= n) return;
    int lane = threadIdx.x & 63;
    half4v v = ((const half4v*)(xw2 + (size_t)node * D))[lane];
    int c = lane * 4;
    float4 as = *(const float4*)(att_s + c);
    float4 ad = *(const float4*)(att_d + c);
    float s1 = (float)v[0] * as.x + (float)v[1] * as.y + (float)v[2] * as.z + (float)v[3] * as.w;
    float s2 = (float)v[0] * ad.x + (float)v[1] * ad.y + (float)v[2] * ad.z + (float)v[3] * ad.w;
    for (int off = 32; off > 0; off >>= 1) {
        s1 += __shfl_down(s1, off);
        s2 += __shfl_down(s2, off);
    }
    if (lane == 0) { asrc[node] = s1; adst[node] = s2; }
}

// ---------------- GAT aggregate: wave-parallel max, register-staged logits ----------------
__global__ void gat_agg(const _Float16* __restrict__ xw2, const int* __restrict__ csr,
                        const int* __restrict__ row_ofs, const float* __restrict__ asrc,
                        const float* __restrict__ adst, const float* __restrict__ b2,
                        float* __restrict__ out, int n) {
    int node = (blockIdx.x << 2) + (threadIdx.x >> 6);
    if (node >= n) return;
    int lane = threadIdx.x & 63;
    float ad = adst[node];
    float e_self = asrc[node] + ad;
    e_self = e_self > 0.f ? e_self : 0.2f * e_self;
    int beg = row_ofs[node], end = row_ofs[node + 1];
    int deg = end - beg;
    int degc = deg < 128 ? deg : 128;
    // stage indices + logits lane-parallel
    int sreg[2];
    float evreg[2];
    float mymax = e_self;
#pragma unroll
    for (int c = 0; c < 2; c++) {
        int i = c * 64 + lane;
        if (i < deg) {
            int s = csr[beg + i];
            float ev = asrc[s] + ad;
            ev = ev > 0.f ? ev : 0.2f * ev;
            sreg[c] = s;
            evreg[c] = ev;
            mymax = mymax > ev ? mymax : ev;
        } else {
            sreg[c] = 0;
            evreg[c] = -1e30f;
        }
    }
    for (int i = 128 + lane; i < deg; i += 64) {  // slow tail max
        int s = csr[beg + i];
        float ev = asrc[s] + ad;
        ev = ev > 0.f ? ev : 0.2f * ev;
        mymax = mymax > ev ? mymax : ev;
    }
#pragma unroll
    for (int off = 1; off < 64; off <<= 1) {
        float o = __shfl_xor(mymax, off);
        mymax = mymax > o ? mymax : o;
    }
    float m = mymax;
    // pass 2: weighted sum with fixed m
    float ax[UN][4];
    float ps[UN];
#pragma unroll
    for (int j = 0; j < UN; j++) { ax[j][0] = ax[j][1] = ax[j][2] = ax[j][3] = 0.f; ps[j] = 0.f; }
    {   // self loop
        float w = __expf(e_self - m);
        half4v v = ((const half4v*)(xw2 + (size_t)node * D))[lane];
        ax[0][0] = (float)v[0] * w; ax[0][1] = (float)v[1] * w;
        ax[0][2] = (float)v[2] * w; ax[0][3] = (float)v[3] * w;
        ps[0] = w;
    }
    for (int c = 0; c * 64 < degc; c++) {
        int cs = sreg[c];
        float cev = evreg[c];
        int lim = degc - c * 64;
        if (lim > 64) lim = 64;
        int i = 0;
        for (; i + UN <= lim; i += UN) {
#pragma unroll
            for (int j = 0; j < UN; j++) {
                int s = __shfl(cs, i + j);
                float ev = __shfl(cev, i + j);
                float w = __expf(ev - m);
                half4v u = ((const half4v*)(xw2 + (size_t)s * D))[lane];
                ps[j] += w;
                ax[j][0] += (float)u[0] * w; ax[j][1] += (float)u[1] * w;
                ax[j][2] += (float)u[2] * w; ax[j][3] += (float)u[3] * w;
            }
        }
        for (; i < lim; i++) {
            int s = __shfl(cs, i);
            float ev = __shfl(cev, i);
            float w = __expf(ev - m);
            half4v u = ((const half4v*)(xw2 + (size_t)s * D))[lane];
            ps[0] += w;
            ax[0][0] += (float)u[0] * w; ax[0][1] += (float)u[1] * w;
            ax[0][2] += (float)u[2] * w; ax[0][3] += (float)u[3] * w;
        }
    }
    for (int e = beg + 128; e < end; e++) {  // slow tail (deg>128; absent here)
        int s = csr[e];
        float ev = asrc[s] + ad;
        ev = ev > 0.f ? ev : 0.2f * ev;
        float w = __expf(ev - m);
        half4v u = ((const half4v*)(xw2 + (size_t)s * D))[lane];
        ps[0] += w;
        ax[0][0] += (float)u[0] * w; ax[0][1] += (float)u[1] * w;
        ax[0][2] += (float)u[2] * w; ax[0][3] += (float)u[3] * w;
    }
    float a0 = 0.f, a1 = 0.f, a2 = 0.f, a3 = 0.f, ssum = 0.f;
#pragma unroll
    for (int j = 0; j < UN; j++) {
        a0 += ax[j][0]; a1 += ax[j][1]; a2 += ax[j][2]; a3 += ax[j][3]; ssum += ps[j];
    }
    float inv = 1.0f / (ssum + 1e-16f);
    int c4 = lane * 4;
    float4 bb = *(const float4*)(b2 + c4);
    float r0 = a0 * inv + bb.x;
    float r1 = a1 * inv + bb.y;
    float r2 = a2 * inv + bb.z;
    float r3 = a3 * inv + bb.w;
    r0 = r0 > 0.f ? r0 : 0.f;
    r1 = r1 > 0.f ? r1 : 0.f;
    r2 = r2 > 0.f ? r2 : 0.f;
    r3 = r3 > 0.f ? r3 : 0.f;
    *(float4*)(out + (size_t)node * D + c4) = make_float4(r0, r1, r2, r3);
}

// ---------------- launch ----------------

extern "C" void kernel_launch(void* const* d_in, const int* in_sizes, int n_in,
                              void* d_out, int out_size, void* d_ws, size_t ws_size,
                              hipStream_t stream) {
    const float* emb = (const float*)d_in[0];
    const int*   ei  = (const int*)d_in[1];
    const float* W1  = (const float*)d_in[2];
    const float* b1  = (const float*)d_in[3];
    const float* W2  = (const float*)d_in[4];
    const float* atS = (const float*)d_in[5];
    const float* atD = (const float*)d_in[6];
    const float* b2  = (const float*)d_in[7];

    int n = in_sizes[0] / D;  // 10000
    int E = in_sizes[1] / 2;  // 320000
    const int* src = ei;
    const int* dst = ei + E;

    char* w = (char*)d_ws;
    auto alloc = [&](size_t bytes) -> char* {
        char* p = w;
        w += (bytes + 255) & ~(size_t)255;
        return p;
    };
    int*      cnt     = (int*)alloc((size_t)n * 4);
    int*      row_ofs = (int*)alloc((size_t)(n + 1) * 4);
    int*      cursor  = (int*)alloc((size_t)n * 4);
    float*    dinv    = (float*)alloc((size_t)n * 4);
    int*      csr     = (int*)alloc((size_t)E * 4);
    _Float16* w1thi   = (_Float16*)alloc((size_t)D * D * 2);
    _Float16* w1tlo   = (_Float16*)alloc((size_t)D * D * 2);
    _Float16* w2thi   = (_Float16*)alloc((size_t)D * D * 2);
    _Float16* w2tlo   = (_Float16*)alloc((size_t)D * D * 2);
    _Float16* ahi     = (_Float16*)alloc((size_t)n * D * 2);
    _Float16* alo     = (_Float16*)alloc((size_t)n * D * 2);
    _Float16* xw1h    = (_Float16*)alloc((size_t)n * D * 2);
    _Float16* x1hi    = (_Float16*)alloc((size_t)n * D * 2);
    _Float16* x1lo    = (_Float16*)alloc((size_t)n * D * 2);
    float*    asrc    = (float*)alloc((size_t)n * 4);
    float*    adst    = (float*)alloc((size_t)n * 4);
    _Float16* xw2h    = xw1h;  // xw1h dead after gcn_agg

    hipMemsetAsync(cnt, 0, (size_t)n * 4, stream);
    int eb = (E + 255) / 256;
    count_deg<<<eb, 256, 0, stream>>>(dst, E, cnt);
    scan_build<<<1, 1024, 0, stream>>>(cnt, row_ofs, cursor, dinv, n);
    fill_csr<<<eb, 256, 0, stream>>>(src, dst, E, cursor, csr);

    prep_w<<<64, 256, 0, stream>>>(W1, w1thi, w1tlo);
    prep_w<<<64, 256, 0, stream>>>(W2, w2thi, w2tlo);
    int total4 = n * D / 4;
    prep_a<<<(total4 + 255) / 256, 256, 0, stream>>>(emb, ahi, alo, total4);

    dim3 ggrid((n / 16 + 3) / 4, D / 16);
    gemm_split<<<ggrid, 256, 0, stream>>>(ahi, alo, w1thi, w1tlo, dinv, xw1h, n);

    int nb = (n + 3) / 4;
    gcn_agg<<<nb, 256, 0, stream>>>(xw1h, csr, row_ofs, dinv, b1, x1hi, x1lo, n);

    gemm_split<<<ggrid, 256, 0, stream>>>(x1hi, x1lo, w2thi, w2tlo, nullptr, xw2h, n);
    att_dots<<<nb, 256, 0, stream>>>(xw2h, atS, atD, asrc, adst, n);
    gat_agg<<<nb, 256, 0, stream>>>(xw2h, csr, row_ofs, asrc, adst, b2, (float*)d_out, n);
}